// Round 1
// baseline (300.971 us; speedup 1.0000x reference)
//
#include <hip/hip_runtime.h>
#include <stdint.h>
#include <stddef.h>

// Problem constants
#define NB 4
#define NL 2048
#define MODEL 512   // = INNER_DIM
#define NH 8
#define HD 64

typedef __attribute__((ext_vector_type(8))) short short8;
typedef __attribute__((ext_vector_type(8))) __bf16 bf16x8;
typedef __attribute__((ext_vector_type(4))) float f32x4;

// round-to-nearest-even fp32 -> bf16 (bit pattern)
static __device__ __forceinline__ unsigned short f2bf(float x) {
  union { float f; unsigned u; } v; v.f = x;
  unsigned r = v.u + 0x7FFFu + ((v.u >> 16) & 1u);
  return (unsigned short)(r >> 16);
}

static __device__ __forceinline__ f32x4 mfma16(short8 a, short8 b, f32x4 c) {
  return __builtin_amdgcn_mfma_f32_16x16x32_bf16(
      __builtin_bit_cast(bf16x8, a), __builtin_bit_cast(bf16x8, b), c, 0, 0, 0);
}

// ---------------------------------------------------------------------------
// GEMM: C[M=8192][N=512] = A[8192][512] * W[512][512]^T   (C[m][n]=sum_k A[m][k]W[n][k])
// MODE 0: C bf16 row-major, scaled
// MODE 1: C bf16 written transposed per head-batch: Vt[b][n][s], n=h*64+d, s=m%2048
// MODE 2: C fp32 row-major
// AT: float (fp32 input, converted to bf16 in staging) or unsigned short (bf16 input)
// grid 256 blocks (64 m-tiles x 4 n-tiles), 256 threads (4 waves, 2x2, 64x64/wave)
// ---------------------------------------------------------------------------
template <int MODE, typename AT>
__global__ __launch_bounds__(256) void gemm512(const AT* __restrict__ A,
                                               const float* __restrict__ W,
                                               void* __restrict__ Cv, float scale) {
  __shared__ unsigned short Alds[128][72];  // +8 pad: row stride 144B -> 2-way banks only
  __shared__ unsigned short Wlds[128][72];

  const int tid = threadIdx.x;
  const int bn = blockIdx.x >> 6;   // 0..3
  const int bm = blockIdx.x & 63;   // 0..63
  const int mbase = bm * 128, nbase = bn * 128;
  const int wid = tid >> 6, lane = tid & 63;
  const int lo = lane & 15, grp = lane >> 4;
  const int wm = wid >> 1, wn = wid & 1;

  f32x4 acc[4][4] = {};

#pragma unroll 1
  for (int kb = 0; kb < 8; ++kb) {  // K=512, BK=64
    // ---- stage A tile [128][64] ----
    if constexpr (sizeof(AT) == 4) {
#pragma unroll
      for (int it = 0; it < 8; ++it) {
        int id = tid + it * 256;            // 0..2047 float4-chunks
        int row = id >> 4, cg = id & 15;    // 16 float4 per row
        float4 v = *(const float4*)((const float*)A + (size_t)(mbase + row) * 512 + kb * 64 + cg * 4);
        ushort4 p;
        p.x = f2bf(v.x); p.y = f2bf(v.y); p.z = f2bf(v.z); p.w = f2bf(v.w);
        *(ushort4*)&Alds[row][cg * 4] = p;
      }
    } else {
#pragma unroll
      for (int it = 0; it < 4; ++it) {
        int id = tid + it * 256;            // 0..1023 16B-chunks
        int row = id >> 3, cg = id & 7;     // 8 x (8 bf16) per row
        uint4 v = *(const uint4*)((const unsigned short*)A + (size_t)(mbase + row) * 512 + kb * 64 + cg * 8);
        *(uint4*)&Alds[row][cg * 8] = v;
      }
    }
    // ---- stage W tile [128][64] (always fp32 source) ----
#pragma unroll
    for (int it = 0; it < 8; ++it) {
      int id = tid + it * 256;
      int row = id >> 4, cg = id & 15;
      float4 v = *(const float4*)(W + (size_t)(nbase + row) * 512 + kb * 64 + cg * 4);
      ushort4 p;
      p.x = f2bf(v.x); p.y = f2bf(v.y); p.z = f2bf(v.z); p.w = f2bf(v.w);
      *(ushort4*)&Wlds[row][cg * 4] = p;
    }
    __syncthreads();

#pragma unroll
    for (int kk = 0; kk < 2; ++kk) {
      short8 aw[4], ba[4];
#pragma unroll
      for (int f = 0; f < 4; ++f)
        aw[f] = *(const short8*)&Wlds[wn * 64 + f * 16 + lo][kk * 32 + grp * 8];
#pragma unroll
      for (int f = 0; f < 4; ++f)
        ba[f] = *(const short8*)&Alds[wm * 64 + f * 16 + lo][kk * 32 + grp * 8];
      // swapped operands: D row-index = W-row (n), D col-index = A-row (m)
#pragma unroll
      for (int mf = 0; mf < 4; ++mf)
#pragma unroll
        for (int nf = 0; nf < 4; ++nf)
          acc[mf][nf] = mfma16(aw[nf], ba[mf], acc[mf][nf]);
    }
    __syncthreads();
  }

  // epilogue: lane holds rows n = n0..n0+3 (consecutive), col m fixed
#pragma unroll
  for (int mf = 0; mf < 4; ++mf)
#pragma unroll
    for (int nf = 0; nf < 4; ++nf) {
      int m = mbase + wm * 64 + mf * 16 + lo;
      int n0 = nbase + wn * 64 + nf * 16 + grp * 4;
      f32x4 a = acc[mf][nf];
      if constexpr (MODE == 0) {
        ushort4 p;
        p.x = f2bf(a[0] * scale); p.y = f2bf(a[1] * scale);
        p.z = f2bf(a[2] * scale); p.w = f2bf(a[3] * scale);
        *(ushort4*)((unsigned short*)Cv + (size_t)m * 512 + n0) = p;
      } else if constexpr (MODE == 1) {
        unsigned short* Vt = (unsigned short*)Cv;
        int b = m >> 11, s = m & 2047;
#pragma unroll
        for (int i = 0; i < 4; ++i)
          Vt[((size_t)b * 512 + n0 + i) * 2048 + s] = f2bf(a[i]);
      } else {
        float4 o;
        o.x = a[0]; o.y = a[1]; o.z = a[2]; o.w = a[3];
        *(float4*)((float*)Cv + (size_t)m * 512 + n0) = o;
      }
    }
}

// ---------------------------------------------------------------------------
// Flash attention. Q,K bf16 [b][token][512] (Q pre-scaled by 1/8);
// Vt bf16 [b][h*64+d][2048]; O bf16 [b][token][512].
// grid = 32 bh * 32 qblocks = 1024 blocks; 256 thr = 4 waves x 16 q-rows.
// Swapped QK^T: scores D[s][q], lane col = q. P via per-wave LDS. K/V from global.
// ---------------------------------------------------------------------------
__global__ __launch_bounds__(256) void attn64(const unsigned short* __restrict__ Qg,
                                              const unsigned short* __restrict__ Kg,
                                              const unsigned short* __restrict__ Vt,
                                              unsigned short* __restrict__ Og) {
  __shared__ unsigned short Plds[4][16][72];  // per-wave P[q=16][s=64], padded

  const int tid = threadIdx.x;
  const int wid = tid >> 6, lane = tid & 63;
  const int lo = lane & 15, grp = lane >> 4;
  const int qb = blockIdx.x & 31;
  const int bh = blockIdx.x >> 5;
  const int b = bh >> 3, h = bh & 7;

  const int qrow = qb * 64 + wid * 16 + lo;  // 0..2047, this lane's q (col index)

  // Q fragments (B-operand): B[k=d][col=q], 8 contiguous d per lane
  short8 qf[2];
#pragma unroll
  for (int kk = 0; kk < 2; ++kk)
    qf[kk] = *(const short8*)(Qg + ((size_t)b * 2048 + qrow) * 512 + h * 64 + kk * 32 + grp * 8);

  const unsigned short* Kbh = Kg + (size_t)b * 2048 * 512 + h * 64;
  const unsigned short* Vbh = Vt + ((size_t)b * 512 + h * 64) * 2048;

  float m_run = -1e30f, l_run = 0.f;
  f32x4 o[4] = {};

#pragma unroll 1
  for (int st = 0; st < 32; ++st) {  // S tiles of 64
    // ---- QK^T: D[s(64)][q(16)] per wave ----
    f32x4 sacc[4] = {};
#pragma unroll
    for (int kk = 0; kk < 2; ++kk) {
      short8 kf[4];
#pragma unroll
      for (int sf = 0; sf < 4; ++sf) {
        int s = st * 64 + sf * 16 + lo;  // A-operand row = s
        kf[sf] = *(const short8*)(Kbh + (size_t)s * 512 + kk * 32 + grp * 8);
      }
#pragma unroll
      for (int sf = 0; sf < 4; ++sf) sacc[sf] = mfma16(kf[sf], qf[kk], sacc[sf]);
    }

    // ---- online softmax over s for q = lo ----
    float tmax = -1e30f;
#pragma unroll
    for (int sf = 0; sf < 4; ++sf)
#pragma unroll
      for (int i = 0; i < 4; ++i) tmax = fmaxf(tmax, sacc[sf][i]);
    tmax = fmaxf(tmax, __shfl_xor(tmax, 16));
    tmax = fmaxf(tmax, __shfl_xor(tmax, 32));
    float mnew = fmaxf(m_run, tmax);
    float alpha = __expf(m_run - mnew);  // 0 on first tile
    float p[4][4];
    float psum = 0.f;
#pragma unroll
    for (int sf = 0; sf < 4; ++sf)
#pragma unroll
      for (int i = 0; i < 4; ++i) {
        p[sf][i] = __expf(sacc[sf][i] - mnew);
        psum += p[sf][i];
      }
    psum += __shfl_xor(psum, 16);
    psum += __shfl_xor(psum, 32);
    l_run = l_run * alpha + psum;
    m_run = mnew;
#pragma unroll
    for (int df = 0; df < 4; ++df)
#pragma unroll
      for (int i = 0; i < 4; ++i) o[df][i] *= alpha;

    // ---- P -> LDS (per-wave), layout P[q][s] so PV B-frag reads are contiguous
#pragma unroll
    for (int sf = 0; sf < 4; ++sf) {
      ushort4 pk;
      pk.x = f2bf(p[sf][0]); pk.y = f2bf(p[sf][1]);
      pk.z = f2bf(p[sf][2]); pk.w = f2bf(p[sf][3]);
      *(ushort4*)&Plds[wid][lo][sf * 16 + grp * 4] = pk;  // s = sf*16+grp*4+i, q = lo
    }
    // cross-lane LDS visibility within the wave
    asm volatile("s_waitcnt lgkmcnt(0)" ::: "memory");

    // ---- PV: O'[d][q] += Vt[d][s] * P[s][q] ----
#pragma unroll
    for (int kk = 0; kk < 2; ++kk) {
      short8 pf = *(const short8*)&Plds[wid][lo][kk * 32 + grp * 8];
      short8 vf[4];
#pragma unroll
      for (int df = 0; df < 4; ++df) {
        int d = df * 16 + lo;  // A-operand row = d
        vf[df] = *(const short8*)(Vbh + (size_t)d * 2048 + st * 64 + kk * 32 + grp * 8);
      }
#pragma unroll
      for (int df = 0; df < 4; ++df) o[df] = mfma16(vf[df], pf, o[df]);
    }
  }

  // ---- finalize: divide by l, store bf16; lane holds d0..d0+3 consecutive, q = lo
  float inv = 1.f / l_run;
#pragma unroll
  for (int df = 0; df < 4; ++df) {
    ushort4 pk;
    pk.x = f2bf(o[df][0] * inv); pk.y = f2bf(o[df][1] * inv);
    pk.z = f2bf(o[df][2] * inv); pk.w = f2bf(o[df][3] * inv);
    *(ushort4*)(Og + ((size_t)b * 2048 + qrow) * 512 + h * 64 + df * 16 + grp * 4) = pk;
  }
}

// ---------------------------------------------------------------------------
extern "C" void kernel_launch(void* const* d_in, const int* in_sizes, int n_in,
                              void* d_out, int out_size, void* d_ws, size_t ws_size,
                              hipStream_t stream) {
  (void)in_sizes; (void)n_in; (void)out_size; (void)ws_size;
  const float* query = (const float*)d_in[0];
  const float* key   = (const float*)d_in[1];
  const float* value = (const float*)d_in[2];
  const float* Wq    = (const float*)d_in[3];
  const float* Wk    = (const float*)d_in[4];
  const float* Wv    = (const float*)d_in[5];
  const float* Wo    = (const float*)d_in[6];

  const size_t TOK = (size_t)NB * NL * MODEL;  // 4,194,304 elements
  unsigned short* Qw = (unsigned short*)d_ws;
  unsigned short* Kw = Qw + TOK;
  unsigned short* Vw = Kw + TOK;  // transposed layout [b][h*64+d][s]
  unsigned short* Aw = Vw + TOK;  // attended, [b][l][512]

  // projections (Q scaled by 1/temperature = 1/8)
  gemm512<0, float><<<256, 256, 0, stream>>>(query, Wq, Qw, 0.125f);
  gemm512<0, float><<<256, 256, 0, stream>>>(key, Wk, Kw, 1.0f);
  gemm512<1, float><<<256, 256, 0, stream>>>(value, Wv, Vw, 1.0f);
  // attention
  attn64<<<1024, 256, 0, stream>>>(Qw, Kw, Vw, Aw);
  // output projection -> fp32
  gemm512<2, unsigned short><<<256, 256, 0, stream>>>(Aw, Wo, (float*)d_out, 1.0f);
}

// Round 2
// 137.089 us; speedup vs baseline: 2.1954x; 2.1954x over previous
//
#include <hip/hip_runtime.h>
#include <stdint.h>
#include <stddef.h>

#define NB 4
#define NL 2048
#define MODEL 512
#define NH 8
#define HD 64

// Q pre-scale: (1/sqrt(64)) * log2(e), so scores are in log2 domain
#define QSCALE 0.18033688011112042f

typedef __attribute__((ext_vector_type(8))) short short8;
typedef __attribute__((ext_vector_type(8))) __bf16 bf16x8;
typedef __attribute__((ext_vector_type(4))) float f32x4;

// round-to-nearest-even fp32 -> bf16 (bit pattern)
static __device__ __forceinline__ unsigned short f2bf(float x) {
  union { float f; unsigned u; } v; v.f = x;
  unsigned r = v.u + 0x7FFFu + ((v.u >> 16) & 1u);
  return (unsigned short)(r >> 16);
}

static __device__ __forceinline__ f32x4 mfma16(short8 a, short8 b, f32x4 c) {
  return __builtin_amdgcn_mfma_f32_16x16x32_bf16(
      __builtin_bit_cast(bf16x8, a), __builtin_bit_cast(bf16x8, b), c, 0, 0, 0);
}

#define GLOAD_LDS(gp, lp)                                                      \
  __builtin_amdgcn_global_load_lds(                                            \
      (const __attribute__((address_space(1))) void*)(gp),                     \
      (__attribute__((address_space(3))) void*)(lp), 16, 0, 0)

// ---------------------------------------------------------------------------
// Merged Q/K/V projection: grid 768 = 3 x 256 blocks, 256 thr (4 waves 2x2).
// C[m][n] = A[m][k] * W[n][k];  which 0: Q bf16 (scaled), 1: K bf16,
// 2: V written transposed Vt[b][n][s].
// ---------------------------------------------------------------------------
__global__ __launch_bounds__(256) void qkv512(const float* __restrict__ Aq,
                                              const float* __restrict__ Ak,
                                              const float* __restrict__ Av,
                                              const float* __restrict__ Wqp,
                                              const float* __restrict__ Wkp,
                                              const float* __restrict__ Wvp,
                                              unsigned short* __restrict__ Qo,
                                              unsigned short* __restrict__ Ko,
                                              unsigned short* __restrict__ Vto) {
  __shared__ unsigned short Alds[128][72];
  __shared__ unsigned short Wlds[128][72];

  const int which = blockIdx.x >> 8;        // 0,1,2
  const int bid = blockIdx.x & 255;
  const float* A = which == 0 ? Aq : which == 1 ? Ak : Av;
  const float* W = which == 0 ? Wqp : which == 1 ? Wkp : Wvp;

  const int tid = threadIdx.x;
  const int bn = bid >> 6;                  // 0..3
  const int bm = bid & 63;                  // 0..63
  const int mbase = bm * 128, nbase = bn * 128;
  const int wid = tid >> 6, lane = tid & 63;
  const int lo = lane & 15, grp = lane >> 4;
  const int wm = wid >> 1, wn = wid & 1;

  f32x4 acc[4][4] = {};

#pragma unroll 1
  for (int kb = 0; kb < 8; ++kb) {
#pragma unroll
    for (int it = 0; it < 8; ++it) {
      int id = tid + it * 256;
      int row = id >> 4, cg = id & 15;
      float4 v = *(const float4*)(A + (size_t)(mbase + row) * 512 + kb * 64 + cg * 4);
      ushort4 p;
      p.x = f2bf(v.x); p.y = f2bf(v.y); p.z = f2bf(v.z); p.w = f2bf(v.w);
      *(ushort4*)&Alds[row][cg * 4] = p;
    }
#pragma unroll
    for (int it = 0; it < 8; ++it) {
      int id = tid + it * 256;
      int row = id >> 4, cg = id & 15;
      float4 v = *(const float4*)(W + (size_t)(nbase + row) * 512 + kb * 64 + cg * 4);
      ushort4 p;
      p.x = f2bf(v.x); p.y = f2bf(v.y); p.z = f2bf(v.z); p.w = f2bf(v.w);
      *(ushort4*)&Wlds[row][cg * 4] = p;
    }
    __syncthreads();

#pragma unroll
    for (int kk = 0; kk < 2; ++kk) {
      short8 aw[4], ba[4];
#pragma unroll
      for (int f = 0; f < 4; ++f)
        aw[f] = *(const short8*)&Wlds[wn * 64 + f * 16 + lo][kk * 32 + grp * 8];
#pragma unroll
      for (int f = 0; f < 4; ++f)
        ba[f] = *(const short8*)&Alds[wm * 64 + f * 16 + lo][kk * 32 + grp * 8];
#pragma unroll
      for (int mf = 0; mf < 4; ++mf)
#pragma unroll
        for (int nf = 0; nf < 4; ++nf)
          acc[mf][nf] = mfma16(aw[nf], ba[mf], acc[mf][nf]);
    }
    __syncthreads();
  }

  const float scale = (which == 0) ? QSCALE : 1.0f;
#pragma unroll
  for (int mf = 0; mf < 4; ++mf)
#pragma unroll
    for (int nf = 0; nf < 4; ++nf) {
      int m = mbase + wm * 64 + mf * 16 + lo;
      int n0 = nbase + wn * 64 + nf * 16 + grp * 4;
      f32x4 a = acc[mf][nf];
      if (which < 2) {
        unsigned short* C = which == 0 ? Qo : Ko;
        ushort4 p;
        p.x = f2bf(a[0] * scale); p.y = f2bf(a[1] * scale);
        p.z = f2bf(a[2] * scale); p.w = f2bf(a[3] * scale);
        *(ushort4*)(C + (size_t)m * 512 + n0) = p;
      } else {
        int b = m >> 11, s = m & 2047;
#pragma unroll
        for (int i = 0; i < 4; ++i)
          Vto[((size_t)b * 512 + n0 + i) * 2048 + s] = f2bf(a[i]);
      }
    }
}

// ---------------------------------------------------------------------------
// Output-projection GEMM (bf16 A, fp32 out), same structure as round 1.
// ---------------------------------------------------------------------------
__global__ __launch_bounds__(256) void gemmWo(const unsigned short* __restrict__ A,
                                              const float* __restrict__ W,
                                              float* __restrict__ C) {
  __shared__ unsigned short Alds[128][72];
  __shared__ unsigned short Wlds[128][72];

  const int tid = threadIdx.x;
  const int bn = blockIdx.x >> 6;
  const int bm = blockIdx.x & 63;
  const int mbase = bm * 128, nbase = bn * 128;
  const int wid = tid >> 6, lane = tid & 63;
  const int lo = lane & 15, grp = lane >> 4;
  const int wm = wid >> 1, wn = wid & 1;

  f32x4 acc[4][4] = {};

#pragma unroll 1
  for (int kb = 0; kb < 8; ++kb) {
#pragma unroll
    for (int it = 0; it < 4; ++it) {
      int id = tid + it * 256;
      int row = id >> 3, cg = id & 7;
      uint4 v = *(const uint4*)(A + (size_t)(mbase + row) * 512 + kb * 64 + cg * 8);
      *(uint4*)&Alds[row][cg * 8] = v;
    }
#pragma unroll
    for (int it = 0; it < 8; ++it) {
      int id = tid + it * 256;
      int row = id >> 4, cg = id & 15;
      float4 v = *(const float4*)(W + (size_t)(nbase + row) * 512 + kb * 64 + cg * 4);
      ushort4 p;
      p.x = f2bf(v.x); p.y = f2bf(v.y); p.z = f2bf(v.z); p.w = f2bf(v.w);
      *(ushort4*)&Wlds[row][cg * 4] = p;
    }
    __syncthreads();

#pragma unroll
    for (int kk = 0; kk < 2; ++kk) {
      short8 aw[4], ba[4];
#pragma unroll
      for (int f = 0; f < 4; ++f)
        aw[f] = *(const short8*)&Wlds[wn * 64 + f * 16 + lo][kk * 32 + grp * 8];
#pragma unroll
      for (int f = 0; f < 4; ++f)
        ba[f] = *(const short8*)&Alds[wm * 64 + f * 16 + lo][kk * 32 + grp * 8];
#pragma unroll
      for (int mf = 0; mf < 4; ++mf)
#pragma unroll
        for (int nf = 0; nf < 4; ++nf)
          acc[mf][nf] = mfma16(aw[nf], ba[mf], acc[mf][nf]);
    }
    __syncthreads();
  }

#pragma unroll
  for (int mf = 0; mf < 4; ++mf)
#pragma unroll
    for (int nf = 0; nf < 4; ++nf) {
      int m = mbase + wm * 64 + mf * 16 + lo;
      int n0 = nbase + wn * 64 + nf * 16 + grp * 4;
      f32x4 a = acc[mf][nf];
      float4 o;
      o.x = a[0]; o.y = a[1]; o.z = a[2]; o.w = a[3];
      *(float4*)(C + (size_t)m * 512 + n0) = o;
    }
}

// ---------------------------------------------------------------------------
// Flash attention, 8 waves x 32 q-rows (block = 256 q). KVBLK = 64.
// K,Vt staged in LDS (double-buffered, global_load_lds w=16, XOR-swizzled via
// pre-swizzled global source). Scores in log2 domain (Q pre-scaled), native
// exp2, defer-max THR=8. P via per-wave padded LDS tile.
// grid 256: bh = bid & 31 (same-head blocks share an XCD's L2), qb = bid >> 5.
// ---------------------------------------------------------------------------
__global__ __launch_bounds__(512) void attn256(const unsigned short* __restrict__ Qg,
                                               const unsigned short* __restrict__ Kg,
                                               const unsigned short* __restrict__ Vt,
                                               unsigned short* __restrict__ Og) {
  __shared__ unsigned short Klds[2][64][64];   // [buf][s][d]  8 KB each
  __shared__ unsigned short Vlds[2][64][64];   // [buf][d][s]
  __shared__ unsigned short Plds[8][32][72];   // per-wave P[q][s], 16B-aligned rows

  const int tid = threadIdx.x;
  const int wid = tid >> 6, lane = tid & 63;
  const int lo = lane & 15, grp = lane >> 4;
  const int bh = blockIdx.x & 31;
  const int qb = blockIdx.x >> 5;
  const int b = bh >> 3, h = bh & 7;

  const unsigned short* Kbh = Kg + (size_t)b * 2048 * 512 + h * 64;
  const unsigned short* Vbh = Vt + ((size_t)b * 512 + h * 64) * 2048;

  // Q fragments: q = qb*256 + wid*32 + f*16 + lo, d-chunk = kk*32 + grp*8
  short8 qf[2][2];
#pragma unroll
  for (int f = 0; f < 2; ++f)
#pragma unroll
    for (int kk = 0; kk < 2; ++kk)
      qf[f][kk] = *(const short8*)(Qg +
          ((size_t)b * 2048 + qb * 256 + wid * 32 + f * 16 + lo) * 512 +
          h * 64 + kk * 32 + grp * 8);

  // staging geometry: wave stages rows wid*8 .. wid*8+7 (1 KB) of each tile.
  // LDS linear chunk (r, c) receives global chunk c ^ (r&7)  (st_8x16 swizzle)
  const int srow = lane >> 3;                  // 0..7
  const int schunk = (lane & 7) ^ srow;        // pre-swizzled source chunk
  const int ldsrow = wid * 8;

  float m[2] = {-1e30f, -1e30f};
  float l[2] = {0.f, 0.f};
  f32x4 o[2][4] = {};

  // prologue: stage tile 0
  {
    int r = ldsrow + srow;
    GLOAD_LDS(Kbh + (size_t)r * 512 + schunk * 8, &Klds[0][ldsrow][0]);
    GLOAD_LDS(Vbh + (size_t)r * 2048 + schunk * 8, &Vlds[0][ldsrow][0]);
  }
  __syncthreads();

  int cur = 0;
#pragma unroll 1
  for (int st = 0; st < 32; ++st) {
    // prefetch next tile into buf^1 (drained by the tile-end barrier)
    if (st < 31) {
      int r = ldsrow + srow;
      GLOAD_LDS(Kbh + (size_t)((st + 1) * 64 + r) * 512 + schunk * 8,
                &Klds[cur ^ 1][ldsrow][0]);
      GLOAD_LDS(Vbh + (size_t)r * 2048 + (st + 1) * 64 + schunk * 8,
                &Vlds[cur ^ 1][ldsrow][0]);
    }

    // ---- QK^T: D[s][q] per q-fragment ----
    f32x4 sacc[2][4] = {};
#pragma unroll
    for (int kk = 0; kk < 2; ++kk) {
      short8 kf[4];
#pragma unroll
      for (int sf = 0; sf < 4; ++sf) {
        int rr = sf * 16 + lo;
        int cc = (kk * 4 + grp) ^ (lo & 7);
        kf[sf] = *(const short8*)&Klds[cur][rr][cc * 8];
      }
#pragma unroll
      for (int sf = 0; sf < 4; ++sf) {
        sacc[0][sf] = mfma16(kf[sf], qf[0][kk], sacc[0][sf]);
        sacc[1][sf] = mfma16(kf[sf], qf[1][kk], sacc[1][sf]);
      }
    }

    // ---- online softmax (log2 domain) ----
#pragma unroll
    for (int f = 0; f < 2; ++f) {
      float a0 = fmaxf(fmaxf(sacc[f][0][0], sacc[f][0][1]), fmaxf(sacc[f][0][2], sacc[f][0][3]));
      float a1 = fmaxf(fmaxf(sacc[f][1][0], sacc[f][1][1]), fmaxf(sacc[f][1][2], sacc[f][1][3]));
      float a2 = fmaxf(fmaxf(sacc[f][2][0], sacc[f][2][1]), fmaxf(sacc[f][2][2], sacc[f][2][3]));
      float a3 = fmaxf(fmaxf(sacc[f][3][0], sacc[f][3][1]), fmaxf(sacc[f][3][2], sacc[f][3][3]));
      float tmax = fmaxf(fmaxf(a0, a1), fmaxf(a2, a3));
      tmax = fmaxf(tmax, __shfl_xor(tmax, 16));
      tmax = fmaxf(tmax, __shfl_xor(tmax, 32));
      // defer-max: only rescale when the running max grew by > 8 (P <= 2^8)
      if (!__all(tmax <= m[f] + 8.f)) {
        float mnew = fmaxf(m[f], tmax);
        float alpha = __builtin_exp2f(m[f] - mnew);
        m[f] = mnew;
        l[f] *= alpha;
#pragma unroll
        for (int df = 0; df < 4; ++df) {
          o[f][df][0] *= alpha; o[f][df][1] *= alpha;
          o[f][df][2] *= alpha; o[f][df][3] *= alpha;
        }
      }
      float psum = 0.f;
#pragma unroll
      for (int sf = 0; sf < 4; ++sf) {
        float p0 = __builtin_exp2f(sacc[f][sf][0] - m[f]);
        float p1 = __builtin_exp2f(sacc[f][sf][1] - m[f]);
        float p2 = __builtin_exp2f(sacc[f][sf][2] - m[f]);
        float p3 = __builtin_exp2f(sacc[f][sf][3] - m[f]);
        psum += (p0 + p1) + (p2 + p3);
        ushort4 pk;
        pk.x = f2bf(p0); pk.y = f2bf(p1); pk.z = f2bf(p2); pk.w = f2bf(p3);
        *(ushort4*)&Plds[wid][f * 16 + lo][sf * 16 + grp * 4] = pk;
      }
      psum += __shfl_xor(psum, 16);
      psum += __shfl_xor(psum, 32);
      l[f] += psum;
    }

    // per-wave P write -> read ordering
    asm volatile("s_waitcnt lgkmcnt(0)" ::: "memory");

    // ---- PV: O[d][q] += Vt[d][s] * P[s][q] ----
#pragma unroll
    for (int kk = 0; kk < 2; ++kk) {
      short8 pf0 = *(const short8*)&Plds[wid][lo][kk * 32 + grp * 8];
      short8 pf1 = *(const short8*)&Plds[wid][16 + lo][kk * 32 + grp * 8];
#pragma unroll
      for (int df = 0; df < 4; ++df) {
        int rr = df * 16 + lo;
        int cc = (kk * 4 + grp) ^ (lo & 7);
        short8 vf = *(const short8*)&Vlds[cur][rr][cc * 8];
        o[0][df] = mfma16(vf, pf0, o[0][df]);
        o[1][df] = mfma16(vf, pf1, o[1][df]);
      }
    }

    __syncthreads();
    cur ^= 1;
  }

  // ---- finalize ----
#pragma unroll
  for (int f = 0; f < 2; ++f) {
    float inv = 1.f / l[f];
    int q = qb * 256 + wid * 32 + f * 16 + lo;
#pragma unroll
    for (int df = 0; df < 4; ++df) {
      ushort4 pk;
      pk.x = f2bf(o[f][df][0] * inv); pk.y = f2bf(o[f][df][1] * inv);
      pk.z = f2bf(o[f][df][2] * inv); pk.w = f2bf(o[f][df][3] * inv);
      *(ushort4*)(Og + ((size_t)b * 2048 + q) * 512 + h * 64 + df * 16 + grp * 4) = pk;
    }
  }
}

// ---------------------------------------------------------------------------
extern "C" void kernel_launch(void* const* d_in, const int* in_sizes, int n_in,
                              void* d_out, int out_size, void* d_ws, size_t ws_size,
                              hipStream_t stream) {
  (void)in_sizes; (void)n_in; (void)out_size; (void)ws_size;
  const float* query = (const float*)d_in[0];
  const float* key   = (const float*)d_in[1];
  const float* value = (const float*)d_in[2];
  const float* Wq    = (const float*)d_in[3];
  const float* Wk    = (const float*)d_in[4];
  const float* Wv    = (const float*)d_in[5];
  const float* Wo    = (const float*)d_in[6];

  const size_t TOK = (size_t)NB * NL * MODEL;
  unsigned short* Qw = (unsigned short*)d_ws;
  unsigned short* Kw = Qw + TOK;
  unsigned short* Vw = Kw + TOK;   // transposed [b][h*64+d][s]
  unsigned short* Aw = Vw + TOK;   // attended [b][l][512]

  qkv512<<<768, 256, 0, stream>>>(query, key, value, Wq, Wk, Wv, Qw, Kw, Vw);
  attn256<<<256, 512, 0, stream>>>(Qw, Kw, Vw, Aw);
  gemmWo<<<256, 256, 0, stream>>>(Aw, Wo, (float*)d_out);
}

// Round 3
// 129.029 us; speedup vs baseline: 2.3326x; 1.0625x over previous
//
#include <hip/hip_runtime.h>
#include <stdint.h>
#include <stddef.h>

#define NB 4
#define NL 2048
#define MODEL 512
#define NH 8
#define HD 64

// Q pre-scale: (1/sqrt(64)) * log2(e) -> scores in log2 domain
#define QSCALE 0.18033688011112042f

typedef __attribute__((ext_vector_type(8))) short short8;
typedef __attribute__((ext_vector_type(8))) __bf16 bf16x8;
typedef __attribute__((ext_vector_type(4))) float f32x4;
typedef __attribute__((ext_vector_type(16))) float f32x16;
typedef __attribute__((ext_vector_type(2))) unsigned int u32x2;

// round-to-nearest-even fp32 -> bf16 (bit pattern)
static __device__ __forceinline__ unsigned short f2bf(float x) {
  union { float f; unsigned u; } v; v.f = x;
  unsigned r = v.u + 0x7FFFu + ((v.u >> 16) & 1u);
  return (unsigned short)(r >> 16);
}

// packed fp32x2 -> bf16x2 (single HW instruction)
static __device__ __forceinline__ unsigned cvtpk(float lo, float hi) {
  unsigned r;
  asm("v_cvt_pk_bf16_f32 %0, %1, %2" : "=v"(r) : "v"(lo), "v"(hi));
  return r;
}

static __device__ __forceinline__ f32x4 mfma16(short8 a, short8 b, f32x4 c) {
  return __builtin_amdgcn_mfma_f32_16x16x32_bf16(
      __builtin_bit_cast(bf16x8, a), __builtin_bit_cast(bf16x8, b), c, 0, 0, 0);
}

static __device__ __forceinline__ f32x16 mfma32(short8 a, short8 b, f32x16 c) {
  return __builtin_amdgcn_mfma_f32_32x32x16_bf16(
      __builtin_bit_cast(bf16x8, a), __builtin_bit_cast(bf16x8, b), c, 0, 0, 0);
}

// 16B LDS helpers over 8B-aligned (odd-16B) padded rows
static __device__ __forceinline__ short8 rd16(const unsigned short* p) {
  union { uint2 u[2]; short8 s; } t;
  t.u[0] = *(const uint2*)p;
  t.u[1] = *(const uint2*)(p + 4);
  return t.s;
}
static __device__ __forceinline__ void wr16(unsigned short* p, uint4 v) {
  uint2 a; a.x = v.x; a.y = v.y;
  uint2 b; b.x = v.z; b.y = v.w;
  *(uint2*)p = a;
  *(uint2*)(p + 4) = b;
}

// ---------------------------------------------------------------------------
// Merged Q/K/V projection: grid 768 = 3 x 256, 256 thr (4 waves 2x2).
// C[m][n] = A[m][k] * W[n][k]; which 0: Q bf16 (scaled), 1: K bf16,
// 2: V transposed Vt[b][n][s].
// ---------------------------------------------------------------------------
__global__ __launch_bounds__(256) void qkv512(const float* __restrict__ Aq,
                                              const float* __restrict__ Ak,
                                              const float* __restrict__ Av,
                                              const float* __restrict__ Wqp,
                                              const float* __restrict__ Wkp,
                                              const float* __restrict__ Wvp,
                                              unsigned short* __restrict__ Qo,
                                              unsigned short* __restrict__ Ko,
                                              unsigned short* __restrict__ Vto) {
  __shared__ unsigned short Alds[128][72];
  __shared__ unsigned short Wlds[128][72];

  const int which = blockIdx.x >> 8;
  const int bid = blockIdx.x & 255;
  const float* A = which == 0 ? Aq : which == 1 ? Ak : Av;
  const float* W = which == 0 ? Wqp : which == 1 ? Wkp : Wvp;

  const int tid = threadIdx.x;
  const int bn = bid & 3;            // low bits: bn-siblings adjacent in time
  const int bm = bid >> 2;
  const int mbase = bm * 128, nbase = bn * 128;
  const int wid = tid >> 6, lane = tid & 63;
  const int lo = lane & 15, grp = lane >> 4;
  const int wm = wid >> 1, wn = wid & 1;

  f32x4 acc[4][4] = {};

#pragma unroll 1
  for (int kb = 0; kb < 8; ++kb) {
#pragma unroll
    for (int it = 0; it < 8; ++it) {
      int id = tid + it * 256;
      int row = id >> 4, cg = id & 15;
      float4 v = *(const float4*)(A + (size_t)(mbase + row) * 512 + kb * 64 + cg * 4);
      uint2 w; w.x = cvtpk(v.x, v.y); w.y = cvtpk(v.z, v.w);
      *(uint2*)&Alds[row][cg * 4] = w;
    }
#pragma unroll
    for (int it = 0; it < 8; ++it) {
      int id = tid + it * 256;
      int row = id >> 4, cg = id & 15;
      float4 v = *(const float4*)(W + (size_t)(nbase + row) * 512 + kb * 64 + cg * 4);
      uint2 w; w.x = cvtpk(v.x, v.y); w.y = cvtpk(v.z, v.w);
      *(uint2*)&Wlds[row][cg * 4] = w;
    }
    __syncthreads();

#pragma unroll
    for (int kk = 0; kk < 2; ++kk) {
      short8 aw[4], ba[4];
#pragma unroll
      for (int f = 0; f < 4; ++f)
        aw[f] = *(const short8*)&Wlds[wn * 64 + f * 16 + lo][kk * 32 + grp * 8];
#pragma unroll
      for (int f = 0; f < 4; ++f)
        ba[f] = *(const short8*)&Alds[wm * 64 + f * 16 + lo][kk * 32 + grp * 8];
#pragma unroll
      for (int mf = 0; mf < 4; ++mf)
#pragma unroll
        for (int nf = 0; nf < 4; ++nf)
          acc[mf][nf] = mfma16(aw[nf], ba[mf], acc[mf][nf]);
    }
    __syncthreads();
  }

  const float scale = (which == 0) ? QSCALE : 1.0f;
#pragma unroll
  for (int mf = 0; mf < 4; ++mf)
#pragma unroll
    for (int nf = 0; nf < 4; ++nf) {
      int m = mbase + wm * 64 + mf * 16 + lo;
      int n0 = nbase + wn * 64 + nf * 16 + grp * 4;
      f32x4 a = acc[mf][nf];
      if (which < 2) {
        unsigned short* C = which == 0 ? Qo : Ko;
        uint2 w;
        w.x = cvtpk(a[0] * scale, a[1] * scale);
        w.y = cvtpk(a[2] * scale, a[3] * scale);
        *(uint2*)(C + (size_t)m * 512 + n0) = w;
      } else {
        int b = m >> 11, s = m & 2047;
#pragma unroll
        for (int i = 0; i < 4; ++i)
          Vto[((size_t)b * 512 + n0 + i) * 2048 + s] = f2bf(a[i]);
      }
    }
}

// ---------------------------------------------------------------------------
// Output projection (bf16 A, fp32 out)
// ---------------------------------------------------------------------------
__global__ __launch_bounds__(256) void gemmWo(const unsigned short* __restrict__ A,
                                              const float* __restrict__ W,
                                              float* __restrict__ C) {
  __shared__ unsigned short Alds[128][72];
  __shared__ unsigned short Wlds[128][72];

  const int tid = threadIdx.x;
  const int bn = blockIdx.x & 3;
  const int bm = blockIdx.x >> 2;
  const int mbase = bm * 128, nbase = bn * 128;
  const int wid = tid >> 6, lane = tid & 63;
  const int lo = lane & 15, grp = lane >> 4;
  const int wm = wid >> 1, wn = wid & 1;

  f32x4 acc[4][4] = {};

#pragma unroll 1
  for (int kb = 0; kb < 8; ++kb) {
#pragma unroll
    for (int it = 0; it < 4; ++it) {
      int id = tid + it * 256;
      int row = id >> 3, cg = id & 7;
      uint4 v = *(const uint4*)(A + (size_t)(mbase + row) * 512 + kb * 64 + cg * 8);
      *(uint4*)&Alds[row][cg * 8] = v;
    }
#pragma unroll
    for (int it = 0; it < 8; ++it) {
      int id = tid + it * 256;
      int row = id >> 4, cg = id & 15;
      float4 v = *(const float4*)(W + (size_t)(nbase + row) * 512 + kb * 64 + cg * 4);
      uint2 w; w.x = cvtpk(v.x, v.y); w.y = cvtpk(v.z, v.w);
      *(uint2*)&Wlds[row][cg * 4] = w;
    }
    __syncthreads();

#pragma unroll
    for (int kk = 0; kk < 2; ++kk) {
      short8 aw[4], ba[4];
#pragma unroll
      for (int f = 0; f < 4; ++f)
        aw[f] = *(const short8*)&Wlds[wn * 64 + f * 16 + lo][kk * 32 + grp * 8];
#pragma unroll
      for (int f = 0; f < 4; ++f)
        ba[f] = *(const short8*)&Alds[wm * 64 + f * 16 + lo][kk * 32 + grp * 8];
#pragma unroll
      for (int mf = 0; mf < 4; ++mf)
#pragma unroll
        for (int nf = 0; nf < 4; ++nf)
          acc[mf][nf] = mfma16(aw[nf], ba[mf], acc[mf][nf]);
    }
    __syncthreads();
  }

#pragma unroll
  for (int mf = 0; mf < 4; ++mf)
#pragma unroll
    for (int nf = 0; nf < 4; ++nf) {
      int m = mbase + wm * 64 + mf * 16 + lo;
      int n0 = nbase + wn * 64 + nf * 16 + grp * 4;
      f32x4 a = acc[mf][nf];
      float4 o;
      o.x = a[0]; o.y = a[1]; o.z = a[2]; o.w = a[3];
      *(float4*)(C + (size_t)m * 512 + n0) = o;
    }
}

// ---------------------------------------------------------------------------
// Flash attention, 32x32x16 MFMA, in-register P (cvt_pk + permlane32_swap).
// 4 waves x 32 q = 128 q/block; grid 512 (2 blocks/CU).
// K, Vt in LDS, rows padded to 76 ushorts (8B-aligned, reduces conflicts),
// double-buffered, T14 reg-staging (load at tile top, ds_write after compute).
// Scores in log2 domain; defer-max THR=8.
// ---------------------------------------------------------------------------
__global__ __launch_bounds__(256, 2) void attn32(const unsigned short* __restrict__ Qg,
                                                 const unsigned short* __restrict__ Kg,
                                                 const unsigned short* __restrict__ Vt,
                                                 unsigned short* __restrict__ Og) {
  __shared__ unsigned short Klds[2][64][76];   // [buf][s][d+pad]
  __shared__ unsigned short Vlds[2][64][76];   // [buf][d][s+pad]

  const int tid = threadIdx.x;
  const int wid = tid >> 6, lane = tid & 63;
  const int ln31 = lane & 31, hl = lane >> 5;
  const int bh = blockIdx.x & 31;
  const int qb = blockIdx.x >> 5;              // 0..15
  const int b = bh >> 3, h = bh & 7;

  const unsigned short* Kbh = Kg + (size_t)b * 2048 * 512 + h * 64;
  const unsigned short* Vbh = Vt + ((size_t)b * 512 + h * 64) * 2048;

  const int q = qb * 128 + wid * 32 + ln31;    // this lane's q-column

  // Q B-fragments: col=q, k(d) = ks*16 + hl*8 + j
  short8 qf[4];
#pragma unroll
  for (int ks = 0; ks < 4; ++ks)
    qf[ks] = *(const short8*)(Qg + ((size_t)b * 2048 + q) * 512 + h * 64 + ks * 16 + hl * 8);

  // staging geometry: wave stages 16 rows of K and V; lane -> (row, chunk)
  const int sr = lane >> 3;                    // 0..7
  const int sc = lane & 7;                     // 16B chunk (8 ushorts)
  const int r0 = wid * 16 + sr, r1 = r0 + 8;

  float mrun = -1e30f, lrun = 0.f;
  f32x16 o[2] = {};

  // ---- prologue: stage tile 0 ----
  {
    uint4 gk0 = *(const uint4*)(Kbh + (size_t)r0 * 512 + sc * 8);
    uint4 gk1 = *(const uint4*)(Kbh + (size_t)r1 * 512 + sc * 8);
    uint4 gv0 = *(const uint4*)(Vbh + (size_t)r0 * 2048 + sc * 8);
    uint4 gv1 = *(const uint4*)(Vbh + (size_t)r1 * 2048 + sc * 8);
    wr16(&Klds[0][r0][sc * 8], gk0);
    wr16(&Klds[0][r1][sc * 8], gk1);
    wr16(&Vlds[0][r0][sc * 8], gv0);
    wr16(&Vlds[0][r1][sc * 8], gv1);
  }
  __syncthreads();

  int cur = 0;
#pragma unroll 1
  for (int st = 0; st < 32; ++st) {
    // T14: issue next tile's global loads now; ds_write them after compute
    uint4 gk0, gk1, gv0, gv1;
    if (st < 31) {
      gk0 = *(const uint4*)(Kbh + (size_t)((st + 1) * 64 + r0) * 512 + sc * 8);
      gk1 = *(const uint4*)(Kbh + (size_t)((st + 1) * 64 + r1) * 512 + sc * 8);
      gv0 = *(const uint4*)(Vbh + (size_t)r0 * 2048 + (st + 1) * 64 + sc * 8);
      gv1 = *(const uint4*)(Vbh + (size_t)r1 * 2048 + (st + 1) * 64 + sc * 8);
    }

    // ---- QK^T: D[s][q], two 32-row s-blocks ----
    f32x16 s0 = {}, s1 = {};
    __builtin_amdgcn_s_setprio(1);
#pragma unroll
    for (int ks = 0; ks < 4; ++ks) {
      short8 k0 = rd16(&Klds[cur][ln31][ks * 16 + hl * 8]);
      short8 k1 = rd16(&Klds[cur][32 + ln31][ks * 16 + hl * 8]);
      s0 = mfma32(k0, qf[ks], s0);
      s1 = mfma32(k1, qf[ks], s1);
    }
    __builtin_amdgcn_s_setprio(0);

    // ---- online softmax (lane owns q; 32 of 64 s-values local) ----
    float mloc = -1e30f;
#pragma unroll
    for (int i = 0; i < 16; ++i) mloc = fmaxf(mloc, fmaxf(s0[i], s1[i]));
    float tmax = fmaxf(mloc, __shfl_xor(mloc, 32));
    if (!__all(tmax <= mrun + 8.f)) {
      float mnew = fmaxf(mrun, tmax);
      float alpha = __builtin_exp2f(mrun - mnew);
      mrun = mnew;
      lrun *= alpha;
#pragma unroll
      for (int i = 0; i < 16; ++i) { o[0][i] *= alpha; o[1][i] *= alpha; }
    }
    float psum = 0.f;
    unsigned c0[8], c1[8];
#pragma unroll
    for (int i = 0; i < 8; ++i) {
      float pa = __builtin_exp2f(s0[2 * i] - mrun);
      float pb = __builtin_exp2f(s0[2 * i + 1] - mrun);
      psum += pa + pb;
      c0[i] = cvtpk(pa, pb);
    }
#pragma unroll
    for (int i = 0; i < 8; ++i) {
      float pa = __builtin_exp2f(s1[2 * i] - mrun);
      float pb = __builtin_exp2f(s1[2 * i + 1] - mrun);
      psum += pa + pb;
      c1[i] = cvtpk(pa, pb);
    }
    psum += __shfl_xor(psum, 32);
    lrun += psum;

    // ---- redistribute P into PV B-fragments (permlane32_swap) ----
    {
      u32x2 r;
      r = __builtin_amdgcn_permlane32_swap(c0[0], c0[2], false, false); c0[0] = r[0]; c0[2] = r[1];
      r = __builtin_amdgcn_permlane32_swap(c0[1], c0[3], false, false); c0[1] = r[0]; c0[3] = r[1];
      r = __builtin_amdgcn_permlane32_swap(c0[4], c0[6], false, false); c0[4] = r[0]; c0[6] = r[1];
      r = __builtin_amdgcn_permlane32_swap(c0[5], c0[7], false, false); c0[5] = r[0]; c0[7] = r[1];
      r = __builtin_amdgcn_permlane32_swap(c1[0], c1[2], false, false); c1[0] = r[0]; c1[2] = r[1];
      r = __builtin_amdgcn_permlane32_swap(c1[1], c1[3], false, false); c1[1] = r[0]; c1[3] = r[1];
      r = __builtin_amdgcn_permlane32_swap(c1[4], c1[6], false, false); c1[4] = r[0]; c1[6] = r[1];
      r = __builtin_amdgcn_permlane32_swap(c1[5], c1[7], false, false); c1[5] = r[0]; c1[7] = r[1];
    }
    short8 pf[4];
    {
      union { unsigned u[4]; short8 s; } t;
      t.u[0] = c0[0]; t.u[1] = c0[1]; t.u[2] = c0[2]; t.u[3] = c0[3]; pf[0] = t.s;
      t.u[0] = c0[4]; t.u[1] = c0[5]; t.u[2] = c0[6]; t.u[3] = c0[7]; pf[1] = t.s;
      t.u[0] = c1[0]; t.u[1] = c1[1]; t.u[2] = c1[2]; t.u[3] = c1[3]; pf[2] = t.s;
      t.u[0] = c1[4]; t.u[1] = c1[5]; t.u[2] = c1[6]; t.u[3] = c1[7]; pf[3] = t.s;
    }

    // ---- PV: O[d][q] += Vt[d][s] * P[s][q] ----
    __builtin_amdgcn_s_setprio(1);
#pragma unroll
    for (int ks = 0; ks < 4; ++ks) {
      short8 v0 = rd16(&Vlds[cur][ln31][ks * 16 + hl * 8]);
      short8 v1 = rd16(&Vlds[cur][32 + ln31][ks * 16 + hl * 8]);
      o[0] = mfma32(v0, pf[ks], o[0]);
      o[1] = mfma32(v1, pf[ks], o[1]);
    }
    __builtin_amdgcn_s_setprio(0);

    // ---- write prefetched tile to back buffer, flip ----
    if (st < 31) {
      int nb = cur ^ 1;
      wr16(&Klds[nb][r0][sc * 8], gk0);
      wr16(&Klds[nb][r1][sc * 8], gk1);
      wr16(&Vlds[nb][r0][sc * 8], gv0);
      wr16(&Vlds[nb][r1][sc * 8], gv1);
    }
    __syncthreads();
    cur ^= 1;
  }

  // ---- finalize ----
  float inv = 1.f / lrun;
#pragma unroll
  for (int dblk = 0; dblk < 2; ++dblk)
#pragma unroll
    for (int rg = 0; rg < 4; ++rg) {
      int d0 = dblk * 32 + rg * 8 + hl * 4;
      uint2 w;
      w.x = cvtpk(o[dblk][rg * 4 + 0] * inv, o[dblk][rg * 4 + 1] * inv);
      w.y = cvtpk(o[dblk][rg * 4 + 2] * inv, o[dblk][rg * 4 + 3] * inv);
      *(uint2*)(Og + ((size_t)b * 2048 + q) * 512 + h * 64 + d0) = w;
    }
}

// ---------------------------------------------------------------------------
extern "C" void kernel_launch(void* const* d_in, const int* in_sizes, int n_in,
                              void* d_out, int out_size, void* d_ws, size_t ws_size,
                              hipStream_t stream) {
  (void)in_sizes; (void)n_in; (void)out_size; (void)ws_size;
  const float* query = (const float*)d_in[0];
  const float* key   = (const float*)d_in[1];
  const float* value = (const float*)d_in[2];
  const float* Wq    = (const float*)d_in[3];
  const float* Wk    = (const float*)d_in[4];
  const float* Wv    = (const float*)d_in[5];
  const float* Wo    = (const float*)d_in[6];

  const size_t TOK = (size_t)NB * NL * MODEL;
  unsigned short* Qw = (unsigned short*)d_ws;
  unsigned short* Kw = Qw + TOK;
  unsigned short* Vw = Kw + TOK;   // transposed [b][h*64+d][s]
  unsigned short* Aw = Vw + TOK;   // attended [b][l][512]

  qkv512<<<768, 256, 0, stream>>>(query, key, value, Wq, Wk, Wv, Qw, Kw, Vw);
  attn32<<<512, 256, 0, stream>>>(Qw, Kw, Vw, Aw);
  gemmWo<<<256, 256, 0, stream>>>(Aw, Wo, (float*)d_out);
}